// Round 7
// baseline (275.456 us; speedup 1.0000x reference)
//
#include <hip/hip_runtime.h>
#include <stdint.h>

// Problem constants (B=8, S=1024, D=256, K=16384)
#define N_ROWS 8192
#define D_DIM  256
#define K_CENT 16384

typedef __attribute__((ext_vector_type(8))) short bf16x8;
typedef __attribute__((ext_vector_type(4))) float f32x4;

// Monotone order-preserving float->uint mapping (all dists finite)
__device__ __forceinline__ uint32_t fkey(float f) {
    uint32_t b = __float_as_uint(f);
    return (b & 0x80000000u) ? ~b : (b | 0x80000000u);
}

// f32 -> bf16 round-to-nearest-even
__device__ __forceinline__ unsigned short f2bf(float f) {
    uint32_t u = __float_as_uint(f);
    uint32_t r = u + 0x7FFFu + ((u >> 16) & 1u);
    return (unsigned short)(r >> 16);
}

__device__ __forceinline__ void gload_lds16(const void* g, void* l) {
    __builtin_amdgcn_global_load_lds(
        (const __attribute__((address_space(1))) void*)g,
        (__attribute__((address_space(3))) void*)l, 16, 0, 0);
}

// ---------------- prep: fused bf16 convert + norms (one wave per row) -------
__global__ __launch_bounds__(256)
void prep_kernel(const float* __restrict__ feat,
                 const float* __restrict__ cent,
                 unsigned short* __restrict__ Abf,
                 unsigned short* __restrict__ Bbf,
                 float* __restrict__ xnorm,
                 float* __restrict__ cnorm) {
    int gtid = blockIdx.x * blockDim.x + threadIdx.x;
    int wave = gtid >> 6;
    int lane = gtid & 63;
    if (wave >= N_ROWS + K_CENT) return;
    const float* src;
    unsigned short* dst;
    float* ndst;
    if (wave < N_ROWS) {
        src = feat + (size_t)wave * D_DIM;
        dst = Abf + (size_t)wave * D_DIM;
        ndst = xnorm + wave;
    } else {
        int r = wave - N_ROWS;
        src = cent + (size_t)r * D_DIM;
        dst = Bbf + (size_t)r * D_DIM;
        ndst = cnorm + r;
    }
    float4 v = ((const float4*)src)[lane];
    float s = v.x * v.x + v.y * v.y + v.z * v.z + v.w * v.w;
    ushort4 o;
    o.x = f2bf(v.x); o.y = f2bf(v.y); o.z = f2bf(v.z); o.w = f2bf(v.w);
    *(ushort4*)(dst + lane * 4) = o;
    #pragma unroll
    for (int off = 32; off >= 1; off >>= 1) s += __shfl_xor(s, off);
    if (lane == 0) *ndst = s;
}

// ------- MFMA dist GEMM: 128x128 tile, BK=32, swapped-operand epilogue ------
#define GBM 128
#define GBN 128
#define GBK 32

__global__ __launch_bounds__(256, 4)
void dist_mfma(const unsigned short* __restrict__ Abf,   // 8192 x 256 bf16
               const unsigned short* __restrict__ Bbf,   // 16384 x 256 bf16
               const float* __restrict__ xnorm,
               const float* __restrict__ cnorm,
               float* __restrict__ dist,                 // 8192 x 16384
               float* __restrict__ blockmins) {          // 8192 x 256 (64-col blocks)
    __shared__ unsigned short As[GBM][GBK];   // 8KB
    __shared__ unsigned short Bs[GBN][GBK];   // 8KB

    const int tid = threadIdx.x;
    const int lane = tid & 63;
    const int w = tid >> 6;
    const int wr = w >> 1, wc = w & 1;         // wave -> 64x64 subtile
    const int row0 = blockIdx.x * GBM;
    const int col0 = blockIdx.y * GBN;
    const int cl = lane & 15, kg = lane >> 4;

    f32x4 zero = {0.f, 0.f, 0.f, 0.f};
    // acc[m][n] holds the TRANSPOSED subtile: lane -> (center col block, feat row)
    f32x4 acc[4][4];
    #pragma unroll
    for (int m = 0; m < 4; ++m)
        #pragma unroll
        for (int n = 0; n < 4; ++n) acc[m][n] = zero;

    for (int kt = 0; kt < D_DIM / GBK; ++kt) {   // 8 iterations
        #pragma unroll
        for (int j = 0; j < 2; ++j) {
            int f = tid + 256 * j;
            int r = f >> 2, kq = f & 3;
            gload_lds16(Abf + (size_t)(row0 + r) * D_DIM + kt * GBK + kq * 8,
                        &As[0][0] + f * 8);
        }
        #pragma unroll
        for (int j = 0; j < 2; ++j) {
            int f = tid + 256 * j;
            int r = f >> 2, kq = f & 3;
            gload_lds16(Bbf + (size_t)(col0 + r) * D_DIM + kt * GBK + kq * 8,
                        &Bs[0][0] + f * 8);
        }
        __syncthreads();

        bf16x8 af[4], bfr[4];
        #pragma unroll
        for (int m = 0; m < 4; ++m)
            af[m] = *(const bf16x8*)&As[wr * 64 + m * 16 + cl][kg * 8];
        #pragma unroll
        for (int n = 0; n < 4; ++n)
            bfr[n] = *(const bf16x8*)&Bs[wc * 64 + n * 16 + cl][kg * 8];

        // swapped operands: transposed C/D layout -> each lane holds 4
        // consecutive center-cols of ONE feature row
        #pragma unroll
        for (int m = 0; m < 4; ++m)
            #pragma unroll
            for (int n = 0; n < 4; ++n)
                acc[m][n] = __builtin_amdgcn_mfma_f32_16x16x32_bf16(
                    bfr[n], af[m], acc[m][n], 0, 0, 0);
        __syncthreads();
    }

    // epilogue: lane owns feat row (cl) x 4 center cols (kg*4+reg) per (m,n)
    const int bcol = blockIdx.y * 2 + wc;

    #pragma unroll
    for (int m = 0; m < 4; ++m) {
        const int row = row0 + wr * 64 + m * 16 + cl;
        const float xn = xnorm[row];
        float* drow = dist + (size_t)row * K_CENT;
        float rmin = 3.4e38f;
        #pragma unroll
        for (int n = 0; n < 4; ++n) {
            const int colb = col0 + wc * 64 + n * 16 + kg * 4;
            float4 cn4 = *(const float4*)&cnorm[colb];
            f32x4 a = acc[m][n];
            float4 d4;
            d4.x = (xn - 2.f * a[0]) + cn4.x;
            d4.y = (xn - 2.f * a[1]) + cn4.y;
            d4.z = (xn - 2.f * a[2]) + cn4.z;
            d4.w = (xn - 2.f * a[3]) + cn4.w;
            *(float4*)(drow + colb) = d4;    // coalesced 16B/lane store
            rmin = fminf(rmin,
                   fminf(fminf(d4.x, d4.y), fminf(d4.z, d4.w)));
        }
        // lanes {cl, cl+16, cl+32, cl+48} share this row
        rmin = fminf(rmin, __shfl_xor(rmin, 16));
        rmin = fminf(rmin, __shfl_xor(rmin, 32));
        if (kg == 0)
            blockmins[(size_t)row * 256 + bcol] = rmin;
    }
}

// -------- recheck: candidate COLUMNS via coalesced dist re-read ---------
// One wave per row; 4 rows per 256-thread block.
__global__ __launch_bounds__(256)
void recheck_finalize(const float* __restrict__ feat,
                      const float* __restrict__ cent,
                      const float* __restrict__ xnorm,
                      const float* __restrict__ cnorm,
                      const float* __restrict__ blockmins,
                      const float* __restrict__ dist,
                      float* __restrict__ quant,
                      float* __restrict__ ids) {
    __shared__ float bms[4][256];
    const int tid = threadIdx.x;
    const int wv = tid >> 6;
    const int lane = tid & 63;
    const int row = blockIdx.x * 4 + wv;

    float4 xv = ((const float4*)(feat + (size_t)row * D_DIM))[lane];
    float4 bm4 = ((const float4*)(blockmins + (size_t)row * 256))[lane];
    ((float4*)&bms[wv][0])[lane] = bm4;   // wave-private LDS region, no barrier

    float gmin = fminf(fminf(bm4.x, bm4.y), fminf(bm4.z, bm4.w));
    #pragma unroll
    for (int off = 32; off >= 1; off >>= 1)
        gmin = fminf(gmin, __shfl_xor(gmin, off));

    // worst-case |bf16dist - exactdist| <= ~0.13 ; 1.0 gives 7x margin
    const float thr = gmin + 1.0f;
    const float xn = xnorm[row];
    const float* drow = dist + (size_t)row * K_CENT;

    unsigned long long best = 0xFFFFFFFFFFFFFFFFull;
    for (int b = 0; b < 256; ++b) {
        if (bms[wv][b] <= thr) {                 // wave-uniform branch
            float d = drow[b * 64 + lane];       // coalesced 256B
            unsigned long long m = __ballot(d <= thr);
            while (m) {                          // wave-uniform candidate loop
                int l = __ffsll((unsigned long long)m) - 1;
                m &= m - 1;
                int c = b * 64 + l;
                float4 cv = ((const float4*)(cent + (size_t)c * D_DIM))[lane];
                float p = fmaf(xv.x, cv.x,
                          fmaf(xv.y, cv.y,
                          fmaf(xv.z, cv.z, xv.w * cv.w)));
                #pragma unroll
                for (int off = 32; off >= 1; off >>= 1)
                    p += __shfl_xor(p, off);     // pairwise tree sum
                float dd = (xn - 2.f * p) + cnorm[c];
                unsigned long long key =
                    ((unsigned long long)fkey(dd) << 32) | (unsigned)c;
                best = (key < best) ? key : best;
            }
        }
    }
    const unsigned bidx = (unsigned)(best & 0xFFFFFFFFu);
    if (lane == 0) ids[row] = (float)bidx;
    float4 v = ((const float4*)(cent + (size_t)bidx * D_DIM))[lane];
    ((float4*)(quant + (size_t)row * D_DIM))[lane] = v;
}

// ============================ launch ============================
extern "C" void kernel_launch(void* const* d_in, const int* in_sizes, int n_in,
                              void* d_out, int out_size, void* d_ws, size_t ws_size,
                              hipStream_t stream) {
    const float* feat = (const float*)d_in[0];   // 8192 x 256
    const float* cent = (const float*)d_in[1];   // 16384 x 256

    float* out = (float*)d_out;
    float* quant = out;                 // 2097152
    float* ids   = out + 2097152;       // 8192
    float* dist  = out + 2105344;       // 8192*16384

    char* ws = (char*)d_ws;
    unsigned short* Abf = (unsigned short*)ws;                       // 4MB
    unsigned short* Bbf = (unsigned short*)(ws + (4u << 20));        // 8MB
    float* blockmins    = (float*)(ws + (12u << 20));                // 8MB
    float* xnorm        = (float*)(ws + (20u << 20));                // 32KB
    float* cnorm        = xnorm + N_ROWS;                            // 64KB

    {
        int waves = N_ROWS + K_CENT;
        prep_kernel<<<(waves * 64 + 255) / 256, 256, 0, stream>>>(
            feat, cent, Abf, Bbf, xnorm, cnorm);
    }

    dist_mfma<<<dim3(N_ROWS / GBM, K_CENT / GBN), 256, 0, stream>>>(
        Abf, Bbf, xnorm, cnorm, dist, blockmins);

    recheck_finalize<<<N_ROWS / 4, 256, 0, stream>>>(
        feat, cent, xnorm, cnorm, blockmins, dist, quant, ids);
}

// Round 8
// 224.042 us; speedup vs baseline: 1.2295x; 1.2295x over previous
//
#include <hip/hip_runtime.h>
#include <stdint.h>

// Problem constants (B=8, S=1024, D=256, K=16384)
#define N_ROWS 8192
#define D_DIM  256
#define K_CENT 16384

typedef __attribute__((ext_vector_type(8))) short bf16x8;
typedef __attribute__((ext_vector_type(4))) float f32x4;

// Monotone order-preserving float->uint mapping (all dists finite)
__device__ __forceinline__ uint32_t fkey(float f) {
    uint32_t b = __float_as_uint(f);
    return (b & 0x80000000u) ? ~b : (b | 0x80000000u);
}

// f32 -> bf16 round-to-nearest-even
__device__ __forceinline__ unsigned short f2bf(float f) {
    uint32_t u = __float_as_uint(f);
    uint32_t r = u + 0x7FFFu + ((u >> 16) & 1u);
    return (unsigned short)(r >> 16);
}

__device__ __forceinline__ void gload_lds16(const void* g, void* l) {
    __builtin_amdgcn_global_load_lds(
        (const __attribute__((address_space(1))) void*)g,
        (__attribute__((address_space(3))) void*)l, 16, 0, 0);
}

// ---------------- prep: fused bf16 convert + norms (one wave per row) -------
__global__ __launch_bounds__(256)
void prep_kernel(const float* __restrict__ feat,
                 const float* __restrict__ cent,
                 unsigned short* __restrict__ Abf,
                 unsigned short* __restrict__ Bbf,
                 float* __restrict__ xnorm,
                 float* __restrict__ cnorm) {
    int gtid = blockIdx.x * blockDim.x + threadIdx.x;
    int wave = gtid >> 6;
    int lane = gtid & 63;
    if (wave >= N_ROWS + K_CENT) return;
    const float* src;
    unsigned short* dst;
    float* ndst;
    if (wave < N_ROWS) {
        src = feat + (size_t)wave * D_DIM;
        dst = Abf + (size_t)wave * D_DIM;
        ndst = xnorm + wave;
    } else {
        int r = wave - N_ROWS;
        src = cent + (size_t)r * D_DIM;
        dst = Bbf + (size_t)r * D_DIM;
        ndst = cnorm + r;
    }
    float4 v = ((const float4*)src)[lane];
    float s = v.x * v.x + v.y * v.y + v.z * v.z + v.w * v.w;
    ushort4 o;
    o.x = f2bf(v.x); o.y = f2bf(v.y); o.z = f2bf(v.z); o.w = f2bf(v.w);
    *(ushort4*)(dst + lane * 4) = o;
    #pragma unroll
    for (int off = 32; off >= 1; off >>= 1) s += __shfl_xor(s, off);
    if (lane == 0) *ndst = s;
}

// -- MFMA dist GEMM: 128x128, BK=32, double-buffered LDS (1 barrier/K-step) --
#define GBM 128
#define GBN 128
#define GBK 32

__global__ __launch_bounds__(256, 2)
void dist_mfma(const unsigned short* __restrict__ Abf,   // 8192 x 256 bf16
               const unsigned short* __restrict__ Bbf,   // 16384 x 256 bf16
               const float* __restrict__ xnorm,
               const float* __restrict__ cnorm,
               float* __restrict__ dist,                 // 8192 x 16384
               float* __restrict__ blockmins) {          // 8192 x 256 (64-col blocks)
    __shared__ unsigned short As[2][GBM][GBK];   // 2 x 8KB
    __shared__ unsigned short Bs[2][GBN][GBK];   // 2 x 8KB

    const int tid = threadIdx.x;
    const int lane = tid & 63;
    const int w = tid >> 6;
    const int wr = w >> 1, wc = w & 1;         // wave -> 64x64 subtile
    const int row0 = blockIdx.x * GBM;
    const int col0 = blockIdx.y * GBN;
    const int cl = lane & 15, kg = lane >> 4;

    // staging addresses (per thread: 2 A chunks + 2 B chunks of 16B)
    const int r0 = tid >> 2, kq0 = tid & 3;
    const int r1 = (tid + 256) >> 2, kq1 = (tid + 256) & 3;
    const unsigned short* gA0 = Abf + (size_t)(row0 + r0) * D_DIM + kq0 * 8;
    const unsigned short* gA1 = Abf + (size_t)(row0 + r1) * D_DIM + kq1 * 8;
    const unsigned short* gB0 = Bbf + (size_t)(col0 + r0) * D_DIM + kq0 * 8;
    const unsigned short* gB1 = Bbf + (size_t)(col0 + r1) * D_DIM + kq1 * 8;

    f32x4 zero = {0.f, 0.f, 0.f, 0.f};
    // acc[m][n]: transposed subtile (lane -> feat row = cl, 4 center cols = kg*4+reg)
    f32x4 acc[4][4];
    #pragma unroll
    for (int m = 0; m < 4; ++m)
        #pragma unroll
        for (int n = 0; n < 4; ++n) acc[m][n] = zero;

    // prologue: stage tile 0 into buffer 0
    gload_lds16(gA0, &As[0][0][0] + tid * 8);
    gload_lds16(gA1, &As[0][0][0] + (tid + 256) * 8);
    gload_lds16(gB0, &Bs[0][0][0] + tid * 8);
    gload_lds16(gB1, &Bs[0][0][0] + (tid + 256) * 8);
    __syncthreads();   // compiler emits vmcnt(0) drain before barrier

    int cur = 0;
    for (int kt = 0; kt < D_DIM / GBK; ++kt) {   // 8 iterations
        // prefetch next tile into the alternate buffer (flies during MFMA)
        if (kt < D_DIM / GBK - 1) {
            const int ko = (kt + 1) * GBK;
            gload_lds16(gA0 + ko, &As[cur ^ 1][0][0] + tid * 8);
            gload_lds16(gA1 + ko, &As[cur ^ 1][0][0] + (tid + 256) * 8);
            gload_lds16(gB0 + ko, &Bs[cur ^ 1][0][0] + tid * 8);
            gload_lds16(gB1 + ko, &Bs[cur ^ 1][0][0] + (tid + 256) * 8);
        }

        bf16x8 af[4], bfr[4];
        #pragma unroll
        for (int m = 0; m < 4; ++m)
            af[m] = *(const bf16x8*)&As[cur][wr * 64 + m * 16 + cl][kg * 8];
        #pragma unroll
        for (int n = 0; n < 4; ++n)
            bfr[n] = *(const bf16x8*)&Bs[cur][wc * 64 + n * 16 + cl][kg * 8];

        // swapped operands: transposed C/D layout -> each lane holds 4
        // consecutive center-cols of ONE feature row
        #pragma unroll
        for (int m = 0; m < 4; ++m)
            #pragma unroll
            for (int n = 0; n < 4; ++n)
                acc[m][n] = __builtin_amdgcn_mfma_f32_16x16x32_bf16(
                    bfr[n], af[m], acc[m][n], 0, 0, 0);

        __syncthreads();   // next buffer staged + this buffer free for re-stage
        cur ^= 1;
    }

    // epilogue: lane owns feat row (cl) x 4 center cols (kg*4+reg) per (m,n)
    const int bcol = blockIdx.y * 2 + wc;

    #pragma unroll
    for (int m = 0; m < 4; ++m) {
        const int row = row0 + wr * 64 + m * 16 + cl;
        const float xn = xnorm[row];
        float* drow = dist + (size_t)row * K_CENT;
        float rmin = 3.4e38f;
        #pragma unroll
        for (int n = 0; n < 4; ++n) {
            const int colb = col0 + wc * 64 + n * 16 + kg * 4;
            float4 cn4 = *(const float4*)&cnorm[colb];
            f32x4 a = acc[m][n];
            float4 d4;
            d4.x = (xn - 2.f * a[0]) + cn4.x;
            d4.y = (xn - 2.f * a[1]) + cn4.y;
            d4.z = (xn - 2.f * a[2]) + cn4.z;
            d4.w = (xn - 2.f * a[3]) + cn4.w;
            *(float4*)(drow + colb) = d4;    // coalesced 16B/lane store
            rmin = fminf(rmin,
                   fminf(fminf(d4.x, d4.y), fminf(d4.z, d4.w)));
        }
        // lanes {cl, cl+16, cl+32, cl+48} share this row
        rmin = fminf(rmin, __shfl_xor(rmin, 16));
        rmin = fminf(rmin, __shfl_xor(rmin, 32));
        if (kg == 0)
            blockmins[(size_t)row * 256 + bcol] = rmin;
    }
}

// -------- recheck: candidate COLUMNS via coalesced dist re-read ---------
// One wave per row; 4 rows per 256-thread block.
__global__ __launch_bounds__(256)
void recheck_finalize(const float* __restrict__ feat,
                      const float* __restrict__ cent,
                      const float* __restrict__ xnorm,
                      const float* __restrict__ cnorm,
                      const float* __restrict__ blockmins,
                      const float* __restrict__ dist,
                      float* __restrict__ quant,
                      float* __restrict__ ids) {
    __shared__ float bms[4][256];
    const int tid = threadIdx.x;
    const int wv = tid >> 6;
    const int lane = tid & 63;
    const int row = blockIdx.x * 4 + wv;

    float4 xv = ((const float4*)(feat + (size_t)row * D_DIM))[lane];
    float4 bm4 = ((const float4*)(blockmins + (size_t)row * 256))[lane];
    ((float4*)&bms[wv][0])[lane] = bm4;   // wave-private LDS region, no barrier

    float gmin = fminf(fminf(bm4.x, bm4.y), fminf(bm4.z, bm4.w));
    #pragma unroll
    for (int off = 32; off >= 1; off >>= 1)
        gmin = fminf(gmin, __shfl_xor(gmin, off));

    // worst-case |bf16dist - exactdist| <= ~0.13 ; 1.0 gives 7x margin
    const float thr = gmin + 1.0f;
    const float xn = xnorm[row];
    const float* drow = dist + (size_t)row * K_CENT;

    unsigned long long best = 0xFFFFFFFFFFFFFFFFull;
    for (int b = 0; b < 256; ++b) {
        if (bms[wv][b] <= thr) {                 // wave-uniform branch
            float d = drow[b * 64 + lane];       // coalesced 256B
            unsigned long long m = __ballot(d <= thr);
            while (m) {                          // wave-uniform candidate loop
                int l = __ffsll((unsigned long long)m) - 1;
                m &= m - 1;
                int c = b * 64 + l;
                float4 cv = ((const float4*)(cent + (size_t)c * D_DIM))[lane];
                float p = fmaf(xv.x, cv.x,
                          fmaf(xv.y, cv.y,
                          fmaf(xv.z, cv.z, xv.w * cv.w)));
                #pragma unroll
                for (int off = 32; off >= 1; off >>= 1)
                    p += __shfl_xor(p, off);     // pairwise tree sum
                float dd = (xn - 2.f * p) + cnorm[c];
                unsigned long long key =
                    ((unsigned long long)fkey(dd) << 32) | (unsigned)c;
                best = (key < best) ? key : best;
            }
        }
    }
    const unsigned bidx = (unsigned)(best & 0xFFFFFFFFu);
    if (lane == 0) ids[row] = (float)bidx;
    float4 v = ((const float4*)(cent + (size_t)bidx * D_DIM))[lane];
    ((float4*)(quant + (size_t)row * D_DIM))[lane] = v;
}

// ============================ launch ============================
extern "C" void kernel_launch(void* const* d_in, const int* in_sizes, int n_in,
                              void* d_out, int out_size, void* d_ws, size_t ws_size,
                              hipStream_t stream) {
    const float* feat = (const float*)d_in[0];   // 8192 x 256
    const float* cent = (const float*)d_in[1];   // 16384 x 256

    float* out = (float*)d_out;
    float* quant = out;                 // 2097152
    float* ids   = out + 2097152;       // 8192
    float* dist  = out + 2105344;       // 8192*16384

    char* ws = (char*)d_ws;
    unsigned short* Abf = (unsigned short*)ws;                       // 4MB
    unsigned short* Bbf = (unsigned short*)(ws + (4u << 20));        // 8MB
    float* blockmins    = (float*)(ws + (12u << 20));                // 8MB
    float* xnorm        = (float*)(ws + (20u << 20));                // 32KB
    float* cnorm        = xnorm + N_ROWS;                            // 64KB

    {
        int waves = N_ROWS + K_CENT;
        prep_kernel<<<(waves * 64 + 255) / 256, 256, 0, stream>>>(
            feat, cent, Abf, Bbf, xnorm, cnorm);
    }

    dist_mfma<<<dim3(N_ROWS / GBM, K_CENT / GBN), 256, 0, stream>>>(
        Abf, Bbf, xnorm, cnorm, dist, blockmins);

    recheck_finalize<<<N_ROWS / 4, 256, 0, stream>>>(
        feat, cent, xnorm, cnorm, blockmins, dist, quant, ids);
}

// Round 10
// 219.051 us; speedup vs baseline: 1.2575x; 1.0228x over previous
//
#include <hip/hip_runtime.h>
#include <stdint.h>

// Problem constants (B=8, S=1024, D=256, K=16384)
#define N_ROWS 8192
#define D_DIM  256
#define K_CENT 16384

typedef __attribute__((ext_vector_type(8))) short bf16x8;
typedef __attribute__((ext_vector_type(4))) float f32x4;

// Monotone order-preserving float->uint mapping (all dists finite)
__device__ __forceinline__ uint32_t fkey(float f) {
    uint32_t b = __float_as_uint(f);
    return (b & 0x80000000u) ? ~b : (b | 0x80000000u);
}

// f32 -> bf16 round-to-nearest-even
__device__ __forceinline__ unsigned short f2bf(float f) {
    uint32_t u = __float_as_uint(f);
    uint32_t r = u + 0x7FFFu + ((u >> 16) & 1u);
    return (unsigned short)(r >> 16);
}

__device__ __forceinline__ void gload_lds16(const void* g, void* l) {
    __builtin_amdgcn_global_load_lds(
        (const __attribute__((address_space(1))) void*)g,
        (__attribute__((address_space(3))) void*)l, 16, 0, 0);
}

// ---------------- prep: fused bf16 convert + norms (one wave per row) -------
__global__ __launch_bounds__(256)
void prep_kernel(const float* __restrict__ feat,
                 const float* __restrict__ cent,
                 unsigned short* __restrict__ Abf,
                 unsigned short* __restrict__ Bbf,
                 float* __restrict__ xnorm,
                 float* __restrict__ cnorm) {
    int gtid = blockIdx.x * blockDim.x + threadIdx.x;
    int wave = gtid >> 6;
    int lane = gtid & 63;
    if (wave >= N_ROWS + K_CENT) return;
    const float* src;
    unsigned short* dst;
    float* ndst;
    if (wave < N_ROWS) {
        src = feat + (size_t)wave * D_DIM;
        dst = Abf + (size_t)wave * D_DIM;
        ndst = xnorm + wave;
    } else {
        int r = wave - N_ROWS;
        src = cent + (size_t)r * D_DIM;
        dst = Bbf + (size_t)r * D_DIM;
        ndst = cnorm + r;
    }
    float4 v = ((const float4*)src)[lane];
    float s = v.x * v.x + v.y * v.y + v.z * v.z + v.w * v.w;
    ushort4 o;
    o.x = f2bf(v.x); o.y = f2bf(v.y); o.z = f2bf(v.z); o.w = f2bf(v.w);
    *(ushort4*)(dst + lane * 4) = o;
    #pragma unroll
    for (int off = 32; off >= 1; off >>= 1) s += __shfl_xor(s, off);
    if (lane == 0) *ndst = s;
}

// ------- MFMA dist GEMM: 128x128 tile, BK=32, nontemporal dist stores -------
#define GBM 128
#define GBN 128
#define GBK 32

__global__ __launch_bounds__(256, 2)
void dist_mfma(const unsigned short* __restrict__ Abf,   // 8192 x 256 bf16
               const unsigned short* __restrict__ Bbf,   // 16384 x 256 bf16
               const float* __restrict__ xnorm,
               const float* __restrict__ cnorm,
               float* __restrict__ dist,                 // 8192 x 16384
               float* __restrict__ blockmins) {          // 8192 x 256 (64-col blocks)
    __shared__ unsigned short As[GBM][GBK];   // 8KB
    __shared__ unsigned short Bs[GBN][GBK];   // 8KB

    const int tid = threadIdx.x;
    const int lane = tid & 63;
    const int w = tid >> 6;
    const int wr = w >> 1, wc = w & 1;         // wave -> 64x64 subtile
    const int row0 = blockIdx.x * GBM;
    const int col0 = blockIdx.y * GBN;
    const int cl = lane & 15, kg = lane >> 4;

    f32x4 zero = {0.f, 0.f, 0.f, 0.f};
    // acc[m][n] holds the TRANSPOSED subtile: lane -> (center col block, feat row)
    f32x4 acc[4][4];
    #pragma unroll
    for (int m = 0; m < 4; ++m)
        #pragma unroll
        for (int n = 0; n < 4; ++n) acc[m][n] = zero;

    for (int kt = 0; kt < D_DIM / GBK; ++kt) {   // 8 iterations
        #pragma unroll
        for (int j = 0; j < 2; ++j) {
            int f = tid + 256 * j;
            int r = f >> 2, kq = f & 3;
            gload_lds16(Abf + (size_t)(row0 + r) * D_DIM + kt * GBK + kq * 8,
                        &As[0][0] + f * 8);
        }
        #pragma unroll
        for (int j = 0; j < 2; ++j) {
            int f = tid + 256 * j;
            int r = f >> 2, kq = f & 3;
            gload_lds16(Bbf + (size_t)(col0 + r) * D_DIM + kt * GBK + kq * 8,
                        &Bs[0][0] + f * 8);
        }
        __syncthreads();

        bf16x8 af[4], bfr[4];
        #pragma unroll
        for (int m = 0; m < 4; ++m)
            af[m] = *(const bf16x8*)&As[wr * 64 + m * 16 + cl][kg * 8];
        #pragma unroll
        for (int n = 0; n < 4; ++n)
            bfr[n] = *(const bf16x8*)&Bs[wc * 64 + n * 16 + cl][kg * 8];

        // swapped operands: transposed C/D layout -> each lane holds 4
        // consecutive center-cols of ONE feature row
        #pragma unroll
        for (int m = 0; m < 4; ++m)
            #pragma unroll
            for (int n = 0; n < 4; ++n)
                acc[m][n] = __builtin_amdgcn_mfma_f32_16x16x32_bf16(
                    bfr[n], af[m], acc[m][n], 0, 0, 0);
        __syncthreads();
    }

    // epilogue: lane owns feat row (cl) x 4 center cols (kg*4+reg) per (m,n)
    // dist stores are NONTEMPORAL (f32x4 = clang ext vector, accepted by the
    // builtin): the 537MB stream must not evict A/B panels from L2.
    const int bcol = blockIdx.y * 2 + wc;

    #pragma unroll
    for (int m = 0; m < 4; ++m) {
        const int row = row0 + wr * 64 + m * 16 + cl;
        const float xn = xnorm[row];
        float* drow = dist + (size_t)row * K_CENT;
        float rmin = 3.4e38f;
        #pragma unroll
        for (int n = 0; n < 4; ++n) {
            const int colb = col0 + wc * 64 + n * 16 + kg * 4;
            float4 cn4 = *(const float4*)&cnorm[colb];
            f32x4 a = acc[m][n];
            f32x4 d4;
            d4[0] = (xn - 2.f * a[0]) + cn4.x;
            d4[1] = (xn - 2.f * a[1]) + cn4.y;
            d4[2] = (xn - 2.f * a[2]) + cn4.z;
            d4[3] = (xn - 2.f * a[3]) + cn4.w;
            __builtin_nontemporal_store(d4, (f32x4*)(drow + colb));
            rmin = fminf(rmin,
                   fminf(fminf(d4[0], d4[1]), fminf(d4[2], d4[3])));
        }
        // lanes {cl, cl+16, cl+32, cl+48} share this row
        rmin = fminf(rmin, __shfl_xor(rmin, 16));
        rmin = fminf(rmin, __shfl_xor(rmin, 32));
        if (kg == 0)
            blockmins[(size_t)row * 256 + bcol] = rmin;
    }
}

// -------- recheck: candidate COLUMNS via coalesced dist re-read ---------
// One wave per row; 4 rows per 256-thread block.
__global__ __launch_bounds__(256)
void recheck_finalize(const float* __restrict__ feat,
                      const float* __restrict__ cent,
                      const float* __restrict__ xnorm,
                      const float* __restrict__ cnorm,
                      const float* __restrict__ blockmins,
                      const float* __restrict__ dist,
                      float* __restrict__ quant,
                      float* __restrict__ ids) {
    __shared__ float bms[4][256];
    const int tid = threadIdx.x;
    const int wv = tid >> 6;
    const int lane = tid & 63;
    const int row = blockIdx.x * 4 + wv;

    float4 xv = ((const float4*)(feat + (size_t)row * D_DIM))[lane];
    float4 bm4 = ((const float4*)(blockmins + (size_t)row * 256))[lane];
    ((float4*)&bms[wv][0])[lane] = bm4;   // wave-private LDS region, no barrier

    float gmin = fminf(fminf(bm4.x, bm4.y), fminf(bm4.z, bm4.w));
    #pragma unroll
    for (int off = 32; off >= 1; off >>= 1)
        gmin = fminf(gmin, __shfl_xor(gmin, off));

    // worst-case |bf16dist - exactdist| <= ~0.13 ; 1.0 gives 7x margin
    const float thr = gmin + 1.0f;
    const float xn = xnorm[row];
    const float* drow = dist + (size_t)row * K_CENT;

    unsigned long long best = 0xFFFFFFFFFFFFFFFFull;
    for (int b = 0; b < 256; ++b) {
        if (bms[wv][b] <= thr) {                 // wave-uniform branch
            float d = drow[b * 64 + lane];       // coalesced 256B
            unsigned long long m = __ballot(d <= thr);
            while (m) {                          // wave-uniform candidate loop
                int l = __ffsll((unsigned long long)m) - 1;
                m &= m - 1;
                int c = b * 64 + l;
                float4 cv = ((const float4*)(cent + (size_t)c * D_DIM))[lane];
                float p = fmaf(xv.x, cv.x,
                          fmaf(xv.y, cv.y,
                          fmaf(xv.z, cv.z, xv.w * cv.w)));
                #pragma unroll
                for (int off = 32; off >= 1; off >>= 1)
                    p += __shfl_xor(p, off);     // pairwise tree sum
                float dd = (xn - 2.f * p) + cnorm[c];
                unsigned long long key =
                    ((unsigned long long)fkey(dd) << 32) | (unsigned)c;
                best = (key < best) ? key : best;
            }
        }
    }
    const unsigned bidx = (unsigned)(best & 0xFFFFFFFFu);
    if (lane == 0) ids[row] = (float)bidx;
    float4 v = ((const float4*)(cent + (size_t)bidx * D_DIM))[lane];
    ((float4*)(quant + (size_t)row * D_DIM))[lane] = v;
}

// ============================ launch ============================
extern "C" void kernel_launch(void* const* d_in, const int* in_sizes, int n_in,
                              void* d_out, int out_size, void* d_ws, size_t ws_size,
                              hipStream_t stream) {
    const float* feat = (const float*)d_in[0];   // 8192 x 256
    const float* cent = (const float*)d_in[1];   // 16384 x 256

    float* out = (float*)d_out;
    float* quant = out;                 // 2097152
    float* ids   = out + 2097152;       // 8192
    float* dist  = out + 2105344;       // 8192*16384

    char* ws = (char*)d_ws;
    unsigned short* Abf = (unsigned short*)ws;                       // 4MB
    unsigned short* Bbf = (unsigned short*)(ws + (4u << 20));        // 8MB
    float* blockmins    = (float*)(ws + (12u << 20));                // 8MB
    float* xnorm        = (float*)(ws + (20u << 20));                // 32KB
    float* cnorm        = xnorm + N_ROWS;                            // 64KB

    {
        int waves = N_ROWS + K_CENT;
        prep_kernel<<<(waves * 64 + 255) / 256, 256, 0, stream>>>(
            feat, cent, Abf, Bbf, xnorm, cnorm);
    }

    dist_mfma<<<dim3(N_ROWS / GBM, K_CENT / GBN), 256, 0, stream>>>(
        Abf, Bbf, xnorm, cnorm, dist, blockmins);

    recheck_finalize<<<N_ROWS / 4, 256, 0, stream>>>(
        feat, cent, xnorm, cnorm, blockmins, dist, quant, ids);
}